// Round 11
// baseline (88.077 us; speedup 1.0000x reference)
//
#include <hip/hip_runtime.h>
#include <hip/hip_bf16.h>

#define QD 512
#define SD 64
#define NCTX 32
#define ROWA 1088              // 512 bf16 key + 64B pad (slot+4/row: conflict-free)
#define ROWB 1152              // 576 bf16 av-column rows
#define ABUF (NCTX * ROWA)     // 34816 B per key buffer

constexpr float EPS_LN = 1e-6f;
constexpr float SLOPE = 0.01f;

typedef __attribute__((ext_vector_type(8))) __bf16 bf16x8;
typedef __attribute__((ext_vector_type(4))) float f32x4;

__device__ __forceinline__ float red64(float v) {
#pragma unroll
    for (int m = 32; m; m >>= 1) v += __shfl_xor(v, m, 64);
    return v;
}

__device__ __forceinline__ float b2f(unsigned short u) {
    unsigned int x = ((unsigned int)u) << 16;
    return __builtin_bit_cast(float, x);
}
__device__ __forceinline__ unsigned short f2bu(float f) {
    __hip_bfloat16 h = __float2bfloat16(f);
    return __builtin_bit_cast(unsigned short, h);
}

__device__ __forceinline__ bf16x8 pack8(float4 a, float4 b) {
    bf16x8 r;
    r[0] = (__bf16)a.x; r[1] = (__bf16)a.y; r[2] = (__bf16)a.z; r[3] = (__bf16)a.w;
    r[4] = (__bf16)b.x; r[5] = (__bf16)b.y; r[6] = (__bf16)b.z; r[7] = (__bf16)b.w;
    return r;
}

struct SpFrag { float4 a0, b0, a1, b1; };

// ---- pipeline building blocks (r10-verified math, refactored) -------------
__device__ __forceinline__ void load_pass(const float* kb, int wave, int lane,
                                          int pass, float4 kr[8]) {
#pragma unroll
    for (int i = 0; i < 4; ++i) {
        const float* krow = kb + (8 * wave + 4 * pass + i) * QD;
        kr[2 * i]     = reinterpret_cast<const float4*>(krow)[2 * lane];
        kr[2 * i + 1] = reinterpret_cast<const float4*>(krow)[2 * lane + 1];
    }
}
__device__ __forceinline__ void write_pass(unsigned char* sA, int wave, int lane,
                                           int pass, const float4 kr[8]) {
#pragma unroll
    for (int i = 0; i < 4; ++i) {
        const int n = 8 * wave + 4 * pass + i;
        *reinterpret_cast<bf16x8*>(&sA[n * ROWA + 16 * lane]) =
            pack8(kr[2 * i], kr[2 * i + 1]);
    }
}
__device__ __forceinline__ SpFrag load_sp(const float* sb, int wave, int lane) {
    SpFrag s;
    s.a0 = s.b0 = s.a1 = s.b1 = make_float4(0.f, 0.f, 0.f, 0.f);
    if (wave < 2) {
        const int arow = 16 * wave + (lane & 15);
        const int qq8 = (lane >> 4) * 8;
        const float* s0p = sb + arow * SD + qq8;
        const float* s1p = sb + arow * SD + 32 + qq8;
        s.a0 = reinterpret_cast<const float4*>(s0p)[0];
        s.b0 = reinterpret_cast<const float4*>(s0p)[1];
        s.a1 = reinterpret_cast<const float4*>(s1p)[0];
        s.b1 = reinterpret_cast<const float4*>(s1p)[1];
    }
    return s;
}
// wave-3 only (caller guards): ql[k] = q . av[0:512,k], f32
__device__ __forceinline__ void ql_compute(const float* qb, const float4* av4,
                                           float* dst, int lane) {
    const float4* q4 = reinterpret_cast<const float4*>(qb);
    float s0 = 0.f, s1 = 0.f, s2 = 0.f, s3 = 0.f;
#pragma unroll
    for (int h = 0; h < 2; ++h) {
        const float4 qv = q4[2 * lane + h];
        const float4 a0 = av4[8 * lane + 4 * h + 0];
        const float4 a1 = av4[8 * lane + 4 * h + 1];
        const float4 a2 = av4[8 * lane + 4 * h + 2];
        const float4 a3 = av4[8 * lane + 4 * h + 3];
        s0 += qv.x * a0.x + qv.y * a1.x + qv.z * a2.x + qv.w * a3.x;
        s1 += qv.x * a0.y + qv.y * a1.y + qv.z * a2.y + qv.w * a3.y;
        s2 += qv.x * a0.z + qv.y * a1.z + qv.z * a2.z + qv.w * a3.z;
        s3 += qv.x * a0.w + qv.y * a1.w + qv.z * a2.w + qv.w * a3.w;
    }
    s0 = red64(s0); s1 = red64(s1); s2 = red64(s2); s3 = red64(s3);
    if (lane == 0) { dst[0] = s0; dst[1] = s1; dst[2] = s2; dst[3] = s3; }
}

__device__ __forceinline__ void mfma_phase(
    const unsigned char* sA, const unsigned char* sB, const SpFrag& sp,
    const float* ql4, float (*s_logit)[4], int wave, int lane)
{
    if (wave >= 2) return;
    const int colB = lane & 15;
    const int kgrp = (lane >> 4) * 16;
    const int arow = 16 * wave + (lane & 15);
    f32x4 acc = {0.f, 0.f, 0.f, 0.f};
    bf16x8 bz;
#pragma unroll
    for (int e = 0; e < 8; ++e) bz[e] = (__bf16)0.0f;
#pragma unroll
    for (int ks = 0; ks < 16; ++ks) {                 // key part, K=512
        const int koff = ks * 64 + kgrp;
        const bf16x8 af =
            *reinterpret_cast<const bf16x8*>(&sA[arow * ROWA + koff]);
        bf16x8 bf = bz;
        if (colB < 4)
            bf = *reinterpret_cast<const bf16x8*>(
                &sB[colB * ROWB + (koff ^ (colB << 4))]);
        acc = __builtin_amdgcn_mfma_f32_16x16x32_bf16(af, bf, acc, 0, 0, 0);
    }
#pragma unroll
    for (int ks = 0; ks < 2; ++ks) {                  // spa part, regs
        const int koff = 1024 + ks * 64 + kgrp;
        const bf16x8 af = (ks == 0) ? pack8(sp.a0, sp.b0) : pack8(sp.a1, sp.b1);
        bf16x8 bf = bz;
        if (colB < 4)
            bf = *reinterpret_cast<const bf16x8*>(
                &sB[colB * ROWB + (koff ^ (colB << 4))]);
        acc = __builtin_amdgcn_mfma_f32_16x16x32_bf16(af, bf, acc, 0, 0, 0);
    }
    if (colB < 4) {
        const float qlk = ql4[colB];
#pragma unroll
        for (int r = 0; r < 4; ++r) {
            const int row = 16 * wave + (lane >> 4) * 4 + r;  // C/D m89 layout
            float v = acc[r] + qlk;
            v = v > 0.f ? v : SLOPE * v;
            s_logit[row][colB] = v;
        }
    }
}

__device__ __forceinline__ void softmax_phase(
    float (*s_logit)[4], float* s_w, int wave, int lane)
{
    if (wave != 0) return;
    const int n = lane & 31;
    float v0 = s_logit[n][0], v1 = s_logit[n][1],
          v2 = s_logit[n][2], v3 = s_logit[n][3];
    float m0 = v0, m1 = v1, m2 = v2, m3 = v3;
#pragma unroll
    for (int m = 16; m; m >>= 1) {
        m0 = fmaxf(m0, __shfl_xor(m0, m, 32));
        m1 = fmaxf(m1, __shfl_xor(m1, m, 32));
        m2 = fmaxf(m2, __shfl_xor(m2, m, 32));
        m3 = fmaxf(m3, __shfl_xor(m3, m, 32));
    }
    float e0 = __expf(v0 - m0), e1 = __expf(v1 - m1),
          e2 = __expf(v2 - m2), e3 = __expf(v3 - m3);
    float st0 = e0, st1 = e1, st2 = e2, st3 = e3;
#pragma unroll
    for (int m = 16; m; m >>= 1) {
        st0 += __shfl_xor(st0, m, 32);
        st1 += __shfl_xor(st1, m, 32);
        st2 += __shfl_xor(st2, m, 32);
        st3 += __shfl_xor(st3, m, 32);
    }
    const float w = 0.25f * (e0 / st0 + e1 / st1 + e2 / st2 + e3 / st3);
    if (lane < 32) s_w[n] = w;
}

// includes one internal __syncthreads (all threads must call)
__device__ __forceinline__ void wsum_phase(
    const unsigned char* sA, const float* s_w, const float* qb,
    const float* lng, const float* lnb, float* yrow,
    float* s_red, int wave, int lane, int t)
{
    const int d0 = 2 * t;
    float acc0 = 0.f, acc1 = 0.f;
#pragma unroll
    for (int n = 0; n < NCTX; ++n) {
        const float wn = s_w[n];
        const unsigned int u =
            *reinterpret_cast<const unsigned int*>(&sA[n * ROWA + 4 * t]);
        acc0 += wn * b2f((unsigned short)(u & 0xffffu));
        acc1 += wn * b2f((unsigned short)(u >> 16));
    }
    const float2 qv = *reinterpret_cast<const float2*>(&qb[d0]);
    const float x0 = 1.f / (1.f + __expf(-acc0)) + qv.x;
    const float x1 = 1.f / (1.f + __expf(-acc1)) + qv.y;

    float sum = red64(x0 + x1);
    float ssq = red64(x0 * x0 + x1 * x1);
    if (lane == 0) { s_red[wave] = sum; s_red[4 + wave] = ssq; }
    __syncthreads();
    sum = s_red[0] + s_red[1] + s_red[2] + s_red[3];
    ssq = s_red[4] + s_red[5] + s_red[6] + s_red[7];
    const float mean = sum * (1.f / QD);
    const float var = ssq * (1.f / QD) - mean * mean;
    const float inv = rsqrtf(var + EPS_LN);
    const float2 gg = *reinterpret_cast<const float2*>(&lng[d0]);
    const float2 bb = *reinterpret_cast<const float2*>(&lnb[d0]);
    float2 o;
    o.x = gg.x * (x0 - mean) * inv + bb.x;
    o.y = gg.y * (x1 - mean) * inv + bb.y;
    *reinterpret_cast<float2*>(&yrow[d0]) = o;
}

// ---------------------------------------------------------------------------
// Kernel A: 2-batch software pipeline (T14). Block g handles batches 2g,2g+1
// with double-buffered key LDS: batch-1 loads issued before batch-0 compute,
// LDS writes split (pass0 after MFMA barrier, pass1 after weighted sum) so
// HBM streams under compute. 2 blocks/CU.
// ---------------------------------------------------------------------------
__global__ __launch_bounds__(256, 2) void attn_fuse(
    const float* __restrict__ key, const float* __restrict__ spa,
    const float* __restrict__ query, const float* __restrict__ av,
    const float* __restrict__ lng, const float* __restrict__ lnb,
    float* __restrict__ yout,
    const float* __restrict__ postw, unsigned short* __restrict__ wb16)
{
    __shared__ __align__(16) unsigned char s_A[2 * ABUF];   // 69632 B
    __shared__ __align__(16) unsigned char s_B[4 * ROWB];   // 4608 B
    __shared__ float s_logit[NCTX][4];
    __shared__ float s_w[NCTX];
    __shared__ float s_red[8];
    __shared__ float s_ql[2][4];

    const int g = blockIdx.x;
    const int b0 = 2 * g, b1 = 2 * g + 1;
    const int t = threadIdx.x;
    const int wave = t >> 6;
    const int lane = t & 63;

    const float* kb0 = key + (size_t)b0 * (NCTX * QD);
    const float* kb1 = key + (size_t)b1 * (NCTX * QD);
    const float* qb0 = query + (size_t)b0 * QD;
    const float* qb1 = query + (size_t)b1 * QD;
    const float* sb0 = spa + (size_t)b0 * (NCTX * SD);
    const float* sb1 = spa + (size_t)b1 * (NCTX * SD);
    const float4* av4 = reinterpret_cast<const float4*>(av);
    unsigned char* sA0 = s_A;
    unsigned char* sA1 = s_A + ABUF;

    // ---- side job: convert 2x64 floats of post_w to bf16 ----
    if (t < 32) {
        const int idx = g * 32 + t;
        const float4 wv = reinterpret_cast<const float4*>(postw)[idx];
        ushort4 h;
        h.x = f2bu(wv.x); h.y = f2bu(wv.y); h.z = f2bu(wv.z); h.w = f2bu(wv.w);
        reinterpret_cast<ushort4*>(wb16)[idx] = h;
    }

    // ================= prologue: stage b0 -> buf0, s_B, ql(b0) ============
    {
        float4 kr[8];
        load_pass(kb0, wave, lane, 0, kr); write_pass(sA0, wave, lane, 0, kr);
        load_pass(kb0, wave, lane, 1, kr); write_pass(sA0, wave, lane, 1, kr);
    }
    SpFrag spc = load_sp(sb0, wave, lane);
    {   // B-matrix: wave w stages av column w, 9 k's per lane
        float avreg[9];
#pragma unroll
        for (int r = 0; r < 9; ++r)
            avreg[r] = av[(size_t)(512 + lane * 9 + r) * 4 + wave];
#pragma unroll
        for (int r = 0; r < 9; ++r) {
            const int k = lane * 9 + r;
            *reinterpret_cast<__bf16*>(
                &s_B[wave * ROWB + ((2 * k) ^ (wave << 4))]) = (__bf16)avreg[r];
        }
    }
    if (wave == 3) ql_compute(qb0, av4, s_ql[0], lane);
    __syncthreads();

    // ================= iteration 0: compute b0, prefetch b1 ===============
    float4 p0[8];
    load_pass(kb1, wave, lane, 0, p0);            // issue early (T14)
    SpFrag spn = load_sp(sb1, wave, lane);
    if (wave == 3) ql_compute(qb1, av4, s_ql[1], lane);
    mfma_phase(sA0, s_B, spc, s_ql[0], s_logit, wave, lane);
    __syncthreads();

    write_pass(sA1, wave, lane, 0, p0);           // lands under softmax
    float4 p1[8];
    load_pass(kb1, wave, lane, 1, p1);            // streams under sm+wsum
    softmax_phase(s_logit, s_w, wave, lane);
    __syncthreads();

    wsum_phase(sA0, s_w, qb0, lng, lnb, yout + (size_t)b0 * QD,
               s_red, wave, lane, t);
    write_pass(sA1, wave, lane, 1, p1);
    __syncthreads();

    // ================= iteration 1: compute b1 ============================
    mfma_phase(sA1, s_B, spn, s_ql[1], s_logit, wave, lane);
    __syncthreads();
    softmax_phase(s_logit, s_w, wave, lane);
    __syncthreads();
    wsum_phase(sA1, s_w, qb1, lng, lnb, yout + (size_t)b1 * QD,
               s_red, wave, lane, t);
}

// ---------------------------------------------------------------------------
// Kernel B: out = Y @ W^T + bias + Y-residual, bf16 MFMA (r10, unchanged).
// ---------------------------------------------------------------------------
__device__ __forceinline__ int swzB(int row, int off) {
    return row * 128 + (off ^ ((row & 7) << 4));
}

__global__ __launch_bounds__(256) void post_gemm(
    const float* __restrict__ Y, const unsigned short* __restrict__ Wb,
    const float* __restrict__ pbias, float* __restrict__ out)
{
    __shared__ __align__(16) unsigned char Ys[64 * 128];
    __shared__ __align__(16) unsigned char Ws[64 * 128];
    const int t = threadIdx.x;
    const int wave = t >> 6, lane = t & 63;
    const int bm = blockIdx.x * 64;
    const int bn = blockIdx.y * 64;

    const int lr = t >> 2;
    const int lq = (t & 3) * 16;

    f32x4 acc[4] = {{0.f,0.f,0.f,0.f},{0.f,0.f,0.f,0.f},
                    {0.f,0.f,0.f,0.f},{0.f,0.f,0.f,0.f}};

    for (int kc = 0; kc < QD; kc += 64) {
        float4 ya[4];
        const float* yrow = Y + (size_t)(bm + lr) * QD + kc + lq;
        const unsigned short* wrow = Wb + (size_t)(bn + lr) * QD + kc + lq;
#pragma unroll
        for (int j = 0; j < 4; ++j)
            ya[j] = reinterpret_cast<const float4*>(yrow)[j];
        const uint4 wa = reinterpret_cast<const uint4*>(wrow)[0];
        const uint4 wb = reinterpret_cast<const uint4*>(wrow)[1];
        __syncthreads();
        const int base = lq * 2;
        *reinterpret_cast<bf16x8*>(&Ys[swzB(lr, base)])      = pack8(ya[0], ya[1]);
        *reinterpret_cast<bf16x8*>(&Ys[swzB(lr, base + 16)]) = pack8(ya[2], ya[3]);
        *reinterpret_cast<uint4*>(&Ws[swzB(lr, base)])       = wa;
        *reinterpret_cast<uint4*>(&Ws[swzB(lr, base + 16)])  = wb;
        __syncthreads();
#pragma unroll
        for (int ks = 0; ks < 2; ++ks) {
            const int ko = ks * 64 + (lane >> 4) * 16;
            const bf16x8 af = *reinterpret_cast<const bf16x8*>(
                &Ys[swzB(16 * wave + (lane & 15), ko)]);
#pragma unroll
            for (int c = 0; c < 4; ++c) {
                const bf16x8 bf = *reinterpret_cast<const bf16x8*>(
                    &Ws[swzB(16 * c + (lane & 15), ko)]);
                acc[c] = __builtin_amdgcn_mfma_f32_16x16x32_bf16(af, bf, acc[c],
                                                                 0, 0, 0);
            }
        }
    }
    const int m0 = bm + 16 * wave + (lane >> 4) * 4;
#pragma unroll
    for (int c = 0; c < 4; ++c) {
        const int n = bn + 16 * c + (lane & 15);
        const float pb = pbias[n];
#pragma unroll
        for (int r = 0; r < 4; ++r) {
            const size_t idx = (size_t)(m0 + r) * QD + n;
            out[idx] = acc[c][r] + pb + Y[idx];
        }
    }
}

// ---------------------------------------------------------------------------
// Kernel C: out = LN(out), in-place row LayerNorm (r10, unchanged).
// ---------------------------------------------------------------------------
__global__ __launch_bounds__(256) void post_ln_kernel(
    float* __restrict__ out,
    const float* __restrict__ lng, const float* __restrict__ lnb)
{
    __shared__ float s_red[8];
    const int r = blockIdx.x;
    const int t = threadIdx.x;
    const int wave = t >> 6, lane = t & 63;
    const int d0 = 2 * t;
    const float2 lv = *reinterpret_cast<const float2*>(&out[(size_t)r * QD + d0]);
    const float x0 = lv.x;
    const float x1 = lv.y;
    float sum = red64(x0 + x1);
    float ssq = red64(x0 * x0 + x1 * x1);
    if (lane == 0) { s_red[wave] = sum; s_red[4 + wave] = ssq; }
    __syncthreads();
    sum = s_red[0] + s_red[1] + s_red[2] + s_red[3];
    ssq = s_red[4] + s_red[5] + s_red[6] + s_red[7];
    const float mean = sum * (1.f / QD);
    const float var = ssq * (1.f / QD) - mean * mean;
    const float inv = rsqrtf(var + EPS_LN);
    const float2 gg = *reinterpret_cast<const float2*>(&lng[d0]);
    const float2 bb = *reinterpret_cast<const float2*>(&lnb[d0]);
    float2 o;
    o.x = gg.x * (x0 - mean) * inv + bb.x;
    o.y = gg.y * (x1 - mean) * inv + bb.y;
    *reinterpret_cast<float2*>(&out[(size_t)r * QD + d0]) = o;
}

// ---------------------------------------------------------------------------
extern "C" void kernel_launch(void* const* d_in, const int* in_sizes, int n_in,
                              void* d_out, int out_size, void* d_ws, size_t ws_size,
                              hipStream_t stream) {
    const float* key    = (const float*)d_in[0];   // [B,32,512]
    const float* spa    = (const float*)d_in[1];   // [B,32,64]
    const float* query  = (const float*)d_in[2];   // [B,512]
    const float* av     = (const float*)d_in[3];   // [1088,4]
    const float* postw  = (const float*)d_in[4];   // [512,512]
    const float* postb  = (const float*)d_in[5];   // [512]
    const float* pre_g  = (const float*)d_in[6];
    const float* pre_b  = (const float*)d_in[7];
    const float* post_g = (const float*)d_in[8];
    const float* post_b = (const float*)d_in[9];
    float* out = (float*)d_out;
    float* yws = (float*)d_ws;                         // y, 8 MB
    unsigned short* wb16 =
        (unsigned short*)((char*)d_ws + (8u << 20));   // W bf16, 512 KB

    const int B = in_sizes[2] / QD;                    // 4096

    attn_fuse<<<B / 2, 256, 0, stream>>>(key, spa, query, av, pre_g, pre_b,
                                         yws, postw, wb16);
    dim3 gridB(B / 64, QD / 64);
    post_gemm<<<gridB, 256, 0, stream>>>(yws, wb16, postb, out);
    post_ln_kernel<<<B, 256, 0, stream>>>(out, post_g, post_b);
}

// Round 13
// 80.916 us; speedup vs baseline: 1.0885x; 1.0885x over previous
//
#include <hip/hip_runtime.h>
#include <hip/hip_bf16.h>

#define QD 512
#define SD 64
#define NCTX 32
#define ROWA 1088              // 512 bf16 key + 64B pad
#define ROWB 1152              // 576 bf16 av-column rows

constexpr float EPS_LN = 1e-6f;
constexpr float SLOPE = 0.01f;

typedef __attribute__((ext_vector_type(8))) __bf16 bf16x8;
typedef __attribute__((ext_vector_type(4))) float f32x4;

__device__ __forceinline__ float red64(float v) {
#pragma unroll
    for (int m = 32; m; m >>= 1) v += __shfl_xor(v, m, 64);
    return v;
}

__device__ __forceinline__ float b2f(unsigned short u) {
    unsigned int x = ((unsigned int)u) << 16;
    return __builtin_bit_cast(float, x);
}
__device__ __forceinline__ unsigned short f2bu(float f) {
    __hip_bfloat16 h = __float2bfloat16(f);
    return __builtin_bit_cast(unsigned short, h);
}

// XOR swizzle: ROWA=1088 alone leaves 16B-region stride 4 mod 8 -> 8-way
// conflict on the 16-row ds_read_b128 of the logit phase; XOR the 16B slot
// with row&7 -> worst case 2-way (free). Staging writes and wsum reads stay
// constant-XOR permutations of contiguous ranges (conflict-free).
__device__ __forceinline__ int swz(int row, int off) {
    return row * ROWA + (off ^ ((row & 7) << 4));
}

__device__ __forceinline__ bf16x8 pack8(float4 a, float4 b) {
    bf16x8 r;
    r[0] = (__bf16)a.x; r[1] = (__bf16)a.y; r[2] = (__bf16)a.z; r[3] = (__bf16)a.w;
    r[4] = (__bf16)b.x; r[5] = (__bf16)b.y; r[6] = (__bf16)b.z; r[7] = (__bf16)b.w;
    return r;
}

// ---------------------------------------------------------------------------
// Kernel A (r10 structure + s_A XOR swizzle), 4 blocks/CU.
// ---------------------------------------------------------------------------
__global__ __launch_bounds__(256, 4) void attn_fuse(
    const float* __restrict__ key, const float* __restrict__ spa,
    const float* __restrict__ query, const float* __restrict__ av,
    const float* __restrict__ lng, const float* __restrict__ lnb,
    float* __restrict__ yout,
    const float* __restrict__ postw, unsigned short* __restrict__ wb16)
{
    __shared__ __align__(16) unsigned char s_A[NCTX * ROWA];  // 34816 B
    __shared__ __align__(16) unsigned char s_B[4 * ROWB];     // 4608 B
    __shared__ float s_logit[NCTX][4];
    __shared__ float s_w[NCTX];
    __shared__ float s_red[8];
    __shared__ float s_ql[4];

    const int b = blockIdx.x;
    const int t = threadIdx.x;
    const int wave = t >> 6;
    const int lane = t & 63;

    const float* kb = key + (size_t)b * (NCTX * QD);
    const float* qb = query + (size_t)b * QD;
    const float* sb = spa + (size_t)b * (NCTX * SD);
    const float4* av4 = reinterpret_cast<const float4*>(av);   // row d -> 4 heads

    // ---- side job: convert 64 floats of post_w to bf16 (grid covers all) ----
    if (t < 16) {
        const float4 wv = reinterpret_cast<const float4*>(postw)[b * 16 + t];
        ushort4 h;
        h.x = f2bu(wv.x); h.y = f2bu(wv.y); h.z = f2bu(wv.z); h.w = f2bu(wv.w);
        reinterpret_cast<ushort4*>(wb16)[b * 16 + t] = h;
    }

    // ================= phase 1: staging ==========
    // key: wave w owns rows 8w..8w+7 (2 passes of 4 rows, VGPR cap)
#pragma unroll
    for (int pass = 0; pass < 2; ++pass) {
        float4 kr[8];
#pragma unroll
        for (int i = 0; i < 4; ++i) {
            const float* krow = kb + (8 * wave + 4 * pass + i) * QD;
            kr[2 * i]     = reinterpret_cast<const float4*>(krow)[2 * lane];
            kr[2 * i + 1] = reinterpret_cast<const float4*>(krow)[2 * lane + 1];
        }
#pragma unroll
        for (int i = 0; i < 4; ++i) {
            const int n = 8 * wave + 4 * pass + i;
            *reinterpret_cast<bf16x8*>(&s_A[swz(n, 16 * lane)]) =
                pack8(kr[2 * i], kr[2 * i + 1]);
        }
    }
    // spa A-fragments for the 2 extra MFMA steps: registers, waves 0/1 only
    float4 sp0a, sp0b, sp1a, sp1b;
    if (wave < 2) {
        const int arow = 16 * wave + (lane & 15);
        const int qq8 = (lane >> 4) * 8;
        const float* s0p = sb + arow * SD + qq8;
        const float* s1p = sb + arow * SD + 32 + qq8;
        sp0a = reinterpret_cast<const float4*>(s0p)[0];
        sp0b = reinterpret_cast<const float4*>(s0p)[1];
        sp1a = reinterpret_cast<const float4*>(s1p)[0];
        sp1b = reinterpret_cast<const float4*>(s1p)[1];
    }
    // B-matrix: wave w stages av column w (heads 0..3), 9 k's per lane
    {
        float avreg[9];
#pragma unroll
        for (int r = 0; r < 9; ++r)
            avreg[r] = av[(size_t)(512 + lane * 9 + r) * 4 + wave];
#pragma unroll
        for (int r = 0; r < 9; ++r) {
            const int k = lane * 9 + r;
            *reinterpret_cast<__bf16*>(
                &s_B[wave * ROWB + ((2 * k) ^ (wave << 4))]) = (__bf16)avreg[r];
        }
    }

    // wave 3: query logit ql[k] = sum_d q[d]*av[d][k]  (f32, n-independent)
    if (wave == 3) {
        const float4* q4 = reinterpret_cast<const float4*>(qb);
        float s0 = 0.f, s1 = 0.f, s2 = 0.f, s3 = 0.f;
#pragma unroll
        for (int h = 0; h < 2; ++h) {
            const float4 qv = q4[2 * lane + h];
            const float4 a0 = av4[8 * lane + 4 * h + 0];
            const float4 a1 = av4[8 * lane + 4 * h + 1];
            const float4 a2 = av4[8 * lane + 4 * h + 2];
            const float4 a3 = av4[8 * lane + 4 * h + 3];
            s0 += qv.x * a0.x + qv.y * a1.x + qv.z * a2.x + qv.w * a3.x;
            s1 += qv.x * a0.y + qv.y * a1.y + qv.z * a2.y + qv.w * a3.y;
            s2 += qv.x * a0.z + qv.y * a1.z + qv.z * a2.z + qv.w * a3.z;
            s3 += qv.x * a0.w + qv.y * a1.w + qv.z * a2.w + qv.w * a3.w;
        }
        s0 = red64(s0); s1 = red64(s1); s2 = red64(s2); s3 = red64(s3);
        if (lane == 0) { s_ql[0] = s0; s_ql[1] = s1; s_ql[2] = s2; s_ql[3] = s3; }
    }
    __syncthreads();

    // ================= phase 2: MFMA logits (waves 0,1) ===================
    if (wave < 2) {
        const int colB = lane & 15;
        const int kgrp = (lane >> 4) * 16;
        const int arow = 16 * wave + colB;
        f32x4 acc = {0.f, 0.f, 0.f, 0.f};
        bf16x8 bz;
#pragma unroll
        for (int e = 0; e < 8; ++e) bz[e] = (__bf16)0.0f;
#pragma unroll
        for (int ks = 0; ks < 16; ++ks) {                 // key part, K=512
            const int koff = ks * 64 + kgrp;
            const bf16x8 af =
                *reinterpret_cast<const bf16x8*>(&s_A[swz(arow, koff)]);
            bf16x8 bf = bz;
            if (colB < 4)
                bf = *reinterpret_cast<const bf16x8*>(
                    &s_B[colB * ROWB + (koff ^ (colB << 4))]);
            acc = __builtin_amdgcn_mfma_f32_16x16x32_bf16(af, bf, acc, 0, 0, 0);
        }
        // spa part, K=512..575 (A-frag from registers)
#pragma unroll
        for (int ks = 0; ks < 2; ++ks) {
            const int koff = 1024 + ks * 64 + kgrp;
            const bf16x8 af = (ks == 0) ? pack8(sp0a, sp0b) : pack8(sp1a, sp1b);
            bf16x8 bf = bz;
            if (colB < 4)
                bf = *reinterpret_cast<const bf16x8*>(
                    &s_B[colB * ROWB + (koff ^ (colB << 4))]);
            acc = __builtin_amdgcn_mfma_f32_16x16x32_bf16(af, bf, acc, 0, 0, 0);
        }
        if (colB < 4) {
            const float qlk = s_ql[colB];
#pragma unroll
            for (int r = 0; r < 4; ++r) {
                const int row = 16 * wave + (lane >> 4) * 4 + r;  // C/D m89 layout
                float v = acc[r] + qlk;
                v = v > 0.f ? v : SLOPE * v;
                s_logit[row][colB] = v;
            }
        }
    }
    __syncthreads();

    // ================= phase 3: softmax over n per head ===================
    if (wave == 0) {
        const int n = lane & 31;
        float v0 = s_logit[n][0], v1 = s_logit[n][1],
              v2 = s_logit[n][2], v3 = s_logit[n][3];
        float m0 = v0, m1 = v1, m2 = v2, m3 = v3;
#pragma unroll
        for (int m = 16; m; m >>= 1) {
            m0 = fmaxf(m0, __shfl_xor(m0, m, 32));
            m1 = fmaxf(m1, __shfl_xor(m1, m, 32));
            m2 = fmaxf(m2, __shfl_xor(m2, m, 32));
            m3 = fmaxf(m3, __shfl_xor(m3, m, 32));
        }
        float e0 = __expf(v0 - m0), e1 = __expf(v1 - m1),
              e2 = __expf(v2 - m2), e3 = __expf(v3 - m3);
        float st0 = e0, st1 = e1, st2 = e2, st3 = e3;
#pragma unroll
        for (int m = 16; m; m >>= 1) {
            st0 += __shfl_xor(st0, m, 32);
            st1 += __shfl_xor(st1, m, 32);
            st2 += __shfl_xor(st2, m, 32);
            st3 += __shfl_xor(st3, m, 32);
        }
        const float w = 0.25f * (e0 / st0 + e1 / st1 + e2 / st2 + e3 / st3);
        if (lane < 32) s_w[n] = w;
    }
    __syncthreads();

    // ======= phase 4: weighted sum, sigmoid, +query residual, pre-LN ======
    const int d0 = 2 * t;
    float acc0 = 0.f, acc1 = 0.f;
#pragma unroll
    for (int n = 0; n < NCTX; ++n) {
        const float wn = s_w[n];
        const unsigned int u =
            *reinterpret_cast<const unsigned int*>(&s_A[swz(n, 4 * t)]);
        acc0 += wn * b2f((unsigned short)(u & 0xffffu));
        acc1 += wn * b2f((unsigned short)(u >> 16));
    }
    const float2 qv = *reinterpret_cast<const float2*>(&qb[d0]);
    const float x0 = 1.f / (1.f + __expf(-acc0)) + qv.x;
    const float x1 = 1.f / (1.f + __expf(-acc1)) + qv.y;

    float sum = red64(x0 + x1);
    float ssq = red64(x0 * x0 + x1 * x1);
    if (lane == 0) { s_red[wave] = sum; s_red[4 + wave] = ssq; }
    __syncthreads();
    sum = s_red[0] + s_red[1] + s_red[2] + s_red[3];
    ssq = s_red[4] + s_red[5] + s_red[6] + s_red[7];
    const float mean = sum * (1.f / QD);
    const float var = ssq * (1.f / QD) - mean * mean;
    const float inv = rsqrtf(var + EPS_LN);
    const float2 gg = *reinterpret_cast<const float2*>(&lng[d0]);
    const float2 bb = *reinterpret_cast<const float2*>(&lnb[d0]);
    float2 o;
    o.x = gg.x * (x0 - mean) * inv + bb.x;
    o.y = gg.y * (x1 - mean) * inv + bb.y;
    *reinterpret_cast<float2*>(&yout[(size_t)b * QD + d0]) = o;
}

// ---------------------------------------------------------------------------
// Kernel B: out = Y @ W^T + bias + Y-residual, bf16 MFMA (r10, unchanged).
// ---------------------------------------------------------------------------
__device__ __forceinline__ int swzB(int row, int off) {
    return row * 128 + (off ^ ((row & 7) << 4));
}

__global__ __launch_bounds__(256) void post_gemm(
    const float* __restrict__ Y, const unsigned short* __restrict__ Wb,
    const float* __restrict__ pbias, float* __restrict__ out)
{
    __shared__ __align__(16) unsigned char Ys[64 * 128];
    __shared__ __align__(16) unsigned char Ws[64 * 128];
    const int t = threadIdx.x;
    const int wave = t >> 6, lane = t & 63;
    const int bm = blockIdx.x * 64;
    const int bn = blockIdx.y * 64;

    const int lr = t >> 2;
    const int lq = (t & 3) * 16;

    f32x4 acc[4] = {{0.f,0.f,0.f,0.f},{0.f,0.f,0.f,0.f},
                    {0.f,0.f,0.f,0.f},{0.f,0.f,0.f,0.f}};

    for (int kc = 0; kc < QD; kc += 64) {
        float4 ya[4];
        const float* yrow = Y + (size_t)(bm + lr) * QD + kc + lq;
        const unsigned short* wrow = Wb + (size_t)(bn + lr) * QD + kc + lq;
#pragma unroll
        for (int j = 0; j < 4; ++j)
            ya[j] = reinterpret_cast<const float4*>(yrow)[j];
        const uint4 wa = reinterpret_cast<const uint4*>(wrow)[0];
        const uint4 wb = reinterpret_cast<const uint4*>(wrow)[1];
        __syncthreads();
        const int base = lq * 2;
        *reinterpret_cast<bf16x8*>(&Ys[swzB(lr, base)])      = pack8(ya[0], ya[1]);
        *reinterpret_cast<bf16x8*>(&Ys[swzB(lr, base + 16)]) = pack8(ya[2], ya[3]);
        *reinterpret_cast<uint4*>(&Ws[swzB(lr, base)])       = wa;
        *reinterpret_cast<uint4*>(&Ws[swzB(lr, base + 16)])  = wb;
        __syncthreads();
#pragma unroll
        for (int ks = 0; ks < 2; ++ks) {
            const int ko = ks * 64 + (lane >> 4) * 16;
            const bf16x8 af = *reinterpret_cast<const bf16x8*>(
                &Ys[swzB(16 * wave + (lane & 15), ko)]);
#pragma unroll
            for (int c = 0; c < 4; ++c) {
                const bf16x8 bf = *reinterpret_cast<const bf16x8*>(
                    &Ws[swzB(16 * c + (lane & 15), ko)]);
                acc[c] = __builtin_amdgcn_mfma_f32_16x16x32_bf16(af, bf, acc[c],
                                                                 0, 0, 0);
            }
        }
    }
    const int m0 = bm + 16 * wave + (lane >> 4) * 4;
#pragma unroll
    for (int c = 0; c < 4; ++c) {
        const int n = bn + 16 * c + (lane & 15);
        const float pb = pbias[n];
#pragma unroll
        for (int r = 0; r < 4; ++r) {
            const size_t idx = (size_t)(m0 + r) * QD + n;
            out[idx] = acc[c][r] + pb + Y[idx];
        }
    }
}

// ---------------------------------------------------------------------------
// Kernel C: out = LN(out), in-place row LayerNorm (r10, unchanged).
// ---------------------------------------------------------------------------
__global__ __launch_bounds__(256) void post_ln_kernel(
    float* __restrict__ out,
    const float* __restrict__ lng, const float* __restrict__ lnb)
{
    __shared__ float s_red[8];
    const int r = blockIdx.x;
    const int t = threadIdx.x;
    const int wave = t >> 6, lane = t & 63;
    const int d0 = 2 * t;
    const float2 lv = *reinterpret_cast<const float2*>(&out[(size_t)r * QD + d0]);
    const float x0 = lv.x;
    const float x1 = lv.y;
    float sum = red64(x0 + x1);
    float ssq = red64(x0 * x0 + x1 * x1);
    if (lane == 0) { s_red[wave] = sum; s_red[4 + wave] = ssq; }
    __syncthreads();
    sum = s_red[0] + s_red[1] + s_red[2] + s_red[3];
    ssq = s_red[4] + s_red[5] + s_red[6] + s_red[7];
    const float mean = sum * (1.f / QD);
    const float var = ssq * (1.f / QD) - mean * mean;
    const float inv = rsqrtf(var + EPS_LN);
    const float2 gg = *reinterpret_cast<const float2*>(&lng[d0]);
    const float2 bb = *reinterpret_cast<const float2*>(&lnb[d0]);
    float2 o;
    o.x = gg.x * (x0 - mean) * inv + bb.x;
    o.y = gg.y * (x1 - mean) * inv + bb.y;
    *reinterpret_cast<float2*>(&out[(size_t)r * QD + d0]) = o;
}

// ---------------------------------------------------------------------------
extern "C" void kernel_launch(void* const* d_in, const int* in_sizes, int n_in,
                              void* d_out, int out_size, void* d_ws, size_t ws_size,
                              hipStream_t stream) {
    const float* key    = (const float*)d_in[0];   // [B,32,512]
    const float* spa    = (const float*)d_in[1];   // [B,32,64]
    const float* query  = (const float*)d_in[2];   // [B,512]
    const float* av     = (const float*)d_in[3];   // [1088,4]
    const float* postw  = (const float*)d_in[4];   // [512,512]
    const float* postb  = (const float*)d_in[5];   // [512]
    const float* pre_g  = (const float*)d_in[6];
    const float* pre_b  = (const float*)d_in[7];
    const float* post_g = (const float*)d_in[8];
    const float* post_b = (const float*)d_in[9];
    float* out = (float*)d_out;
    float* yws = (float*)d_ws;                         // y, 8 MB
    unsigned short* wb16 =
        (unsigned short*)((char*)d_ws + (8u << 20));   // W bf16, 512 KB

    const int B = in_sizes[2] / QD;                    // 4096

    attn_fuse<<<B, 256, 0, stream>>>(key, spa, query, av, pre_g, pre_b, yws,
                                     postw, wb16);
    dim3 gridB(B / 64, QD / 64);
    post_gemm<<<gridB, 256, 0, stream>>>(yws, wb16, postb, out);
    post_ln_kernel<<<B, 256, 0, stream>>>(out, post_g, post_b);
}